// Round 3
// baseline (668.864 us; speedup 1.0000x reference)
//
#include <hip/hip_runtime.h>

// LIIFParametric3DConv — round 15: VALU diet + parallel prep.
// R14 (fragment-ordered weights) confirmed the TA-transaction theory:
// mlp 896->373us, MfmaUtil 32.7%, VALUBusy 48.3%. Remaining costs:
//  (a) prep_kernel was ONE block (serial ~50-150us on 1 CU) -> now 64 blocks.
//  (b) mlp VALU: manual f2bf RNE bit-hack (~11 ops/pair x128) and the
//      30x + 1/(2pi) multiplies around every sin (2 ops x256).
// Fixes: weights pre-scaled by s=30/(2pi) in prep (sin arg is then in
// REVOLUTIONS -> raw v_sin_f32, the same core __sinf uses); unscaled bias /
// t-coord terms fold in via fmaf(s,...,acc) at identical op count; h1 packing
// via v_cvt_pk_bf16_f32 (RNE, bit-identical to f2bf). launch_bounds(256,4).
//
// ws layout (bytes):
//   fhi  @ 0          : 75,497,472  (589824 rows x 64ch bf16, hi)
//   flo  @ 75497472   : 75,497,472  (lo = bf16(f - hi))
//   W1F  @ 150994944  : 32,768      (32 frags x 1KB, fragment-ordered, x s)
//   W1FL @ 151027712  : 32,768      (lo part, x s)
//   W2F  @ 151060480  : 131,072     (128 frags x 1KB, k permuted by R(k2), x s)
//   total 151,191,552

using s16x8 = __attribute__((ext_vector_type(8))) short;
using f32x4 = __attribute__((ext_vector_type(4))) float;
using u32x4 = __attribute__((ext_vector_type(4))) unsigned int;

#define SREV 4.7746482927568600f   // 30/(2*pi)

__device__ __forceinline__ float bf2f(unsigned short u){
  return __uint_as_float(((unsigned)u) << 16);
}
__device__ __forceinline__ short f2bf(float f){
  unsigned b = __float_as_uint(f);
  return (short)((b + 0x7FFFu + ((b >> 16) & 1u)) >> 16);
}
__device__ __forceinline__ float sin_rev(float x){   // sin(2*pi*x)
  float r; asm("v_sin_f32 %0, %1" : "=v"(r) : "v"(x)); return r;
}
__device__ __forceinline__ unsigned cvt_pk_bf16(float lo, float hi){
  unsigned r; asm("v_cvt_pk_bf16_f32 %0, %1, %2" : "=v"(r) : "v"(lo), "v"(hi));
  return r;  // D[15:0]=bf16(lo), D[31:16]=bf16(hi) — matches old pk2(lo,hi)
}

// ---------------- prep: fragment-ordered, pre-scaled weights ----------------
// Grid: 64 blocks x 256 (R14 used 1 block -> ~100us serial on one CU).
// W1 frag f = nt*2+kk (32 frags): lane l elem j -> n = nt*16+(l&15),
//   k = kk*32+(l>>4)*8+j; value = hi/lo bf16 of s*W1[k][n].
// W2 frag f = (cg*4+nt)*8+ks (128 frags): lane l elem j ->
//   n = (f>>5)*64+((f>>3)&3)*16+(l&15), q=l>>4, R=(2*ks+(j>>2))*16+q*4+(j&3);
//   value = bf16(s*W2[R][n]).
__global__ __launch_bounds__(256) void prep_kernel(
    const float* __restrict__ W1, const float* __restrict__ W2,
    short* __restrict__ W1F, short* __restrict__ W1FL, short* __restrict__ W2F){
  const int gid = blockIdx.x*256 + threadIdx.x;   // 0..16383
  {
    const int i = gid;
    const int f = i>>9;
    const int r = i&511;
    const int l = r>>3, j = r&7;
    const int nt = f>>1, kk = f&1;
    const int n = nt*16 + (l&15);
    const int k = kk*32 + (l>>4)*8 + j;
    const float w = W1[(size_t)k*256 + n] * SREV;
    const short h = f2bf(w);
    W1F[i]  = h;
    W1FL[i] = f2bf(w - bf2f((unsigned short)h));
  }
  #pragma unroll
  for(int i=gid; i<65536; i+=16384){
    const int f = i>>9;
    const int r = i&511;
    const int l = r>>3, j = r&7;
    const int ks = f&7;
    const int q  = l>>4;
    const int n  = (f>>5)*64 + ((f>>3)&3)*16 + (l&15);
    const int R  = (2*ks + (j>>2))*16 + q*4 + (j&3);
    W2F[i] = f2bf(W2[(size_t)R*256 + n] * SREV);
  }
}

// ---------------- conv3d 2->64, 3x3x3, SAME; writes hi/lo bf16 --------------
__global__ __launch_bounds__(256) void conv_kernel(
    const float* __restrict__ xr, const float* __restrict__ xi,
    const float* __restrict__ enc_w, const float* __restrict__ enc_b,
    short* __restrict__ fhi, short* __restrict__ flo)
{
  __shared__ __align__(16) float wl[64][56];
  __shared__ float bl[64];
  const int tid = threadIdx.x;
  for(int i=tid;i<3456;i+=256) wl[i/54][i%54] = enc_w[i];
  if(tid<128) wl[tid>>1][54+(tid&1)] = 0.f;
  if(tid<64)  bl[tid] = enc_b[tid];
  __syncthreads();

  const unsigned bi   = blockIdx.x;          // 2304 = 2*32*36
  const unsigned tile = bi % 36u;
  const unsigned t    = (bi/36u) % 32u;
  const unsigned b    = bi / 1152u;
  const int h = (int)((tile/6u)*16u) + (tid>>4);
  const int w = (int)((tile%6u)*16u) + (tid&15);

  float xv[56];
  xv[54]=0.f; xv[55]=0.f;
  int k=0;
  #pragma unroll
  for(int i=0;i<2;i++){
    const float* src = i ? xi : xr;
    #pragma unroll
    for(int dz=-1;dz<=1;dz++){
      const int tt = (int)t + dz;
      const bool tok = (tt>=0 && tt<32);
      const size_t tbase = (size_t)(b*32u + (unsigned)(tok?tt:0))*9216u;
      #pragma unroll
      for(int dy=-1;dy<=1;dy++){
        const int hh = h+dy;
        const bool hok = (hh>=0 && hh<96);
        #pragma unroll
        for(int dx=-1;dx<=1;dx++){
          const int ww = w+dx;
          const bool ok = tok && hok && (ww>=0 && ww<96);
          xv[k] = ok ? src[tbase + (size_t)(hh*96+ww)] : 0.f;
          k++;
        }
      }
    }
  }

  const unsigned idx = (b*32u+t)*9216u + (unsigned)(h*96+w);
  short* ph = fhi + (size_t)idx*64u;
  short* pl = flo + (size_t)idx*64u;
  #pragma unroll
  for(int g=0; g<4; g++){
    unsigned hw[8], lw[8];
    #pragma unroll
    for(int c2=0;c2<8;c2++){
      unsigned hpair=0, lpair=0;
      #pragma unroll
      for(int half=0; half<2; half++){
        const int c = g*16 + c2*2 + half;
        float acc = bl[c];
        const float4* wp = (const float4*)(&wl[c][0]);
        #pragma unroll
        for(int qq=0;qq<14;qq++){
          const float4 w4 = wp[qq];
          acc += w4.x*xv[qq*4+0] + w4.y*xv[qq*4+1]
               + w4.z*xv[qq*4+2] + w4.w*xv[qq*4+3];
        }
        const unsigned short hu = (unsigned short)f2bf(acc);
        const unsigned short lu = (unsigned short)f2bf(acc - bf2f(hu));
        hpair |= ((unsigned)hu) << (16*half);
        lpair |= ((unsigned)lu) << (16*half);
      }
      hw[c2]=hpair; lw[c2]=lpair;
    }
    uint4* dh = (uint4*)(ph + g*16);
    uint4* dl = (uint4*)(pl + g*16);
    dh[0] = make_uint4(hw[0],hw[1],hw[2],hw[3]);
    dh[1] = make_uint4(hw[4],hw[5],hw[6],hw[7]);
    dl[0] = make_uint4(lw[0],lw[1],lw[2],lw[3]);
    dl[1] = make_uint4(lw[4],lw[5],lw[6],lw[7]);
  }
}

// ---------------- fused SIREN MLP + lerp, MFMA 16x16x32 bf16 ----------------
// Block: 4 waves x 32 rows (evals). No LDS, no barriers. Weight loads
// fragment-ordered: base + f*1024 + lane*16. Weights pre-scaled by SREV so
// sin args are in revolutions -> raw v_sin_f32, packing via v_cvt_pk_bf16_f32.
__global__ __launch_bounds__(256, 4) void mlp_kernel(
  const float* __restrict__ tcoord,
  const short* __restrict__ fhi, const short* __restrict__ flo,
  const short* __restrict__ W1F, const short* __restrict__ W1FL,
  const float* __restrict__ W1,  const float* __restrict__ b1,
  const short* __restrict__ W2F, const float* __restrict__ b2,
  const float* __restrict__ W3,  const float* __restrict__ b3,
  float* __restrict__ out)
{
  const int tid  = threadIdx.x;
  const int wave = tid>>6;
  const int lane = tid&63;
  const int q  = lane>>4;   // quad
  const int ln = lane&15;
  const unsigned evbase = blockIdx.x*128u + (unsigned)wave*32u;

  // ---- per-lane meta for row (lane&31) ----
  const unsigned rrow = (unsigned)(lane & 31);
  const unsigned ev = evbase + rrow;
  const unsigned pt = ev>>1;
  const unsigned fc = ev&1u;
  const unsigned wq = pt%96u;
  const unsigned hq = (pt/96u)%96u;
  const unsigned jq = (pt/9216u)%32u;
  const unsigned bq = pt/294912u;
  float tc = tcoord[bq*32u+jq];
  tc = fminf(fmaxf(tc, -1.0f), 1.0f - 1e-6f);
  const float dstep = 2.0f/31.0f;
  const int ti = (int)floorf((tc+1.0f)/dstep);
  const unsigned trow = (unsigned)ti + fc;       // <= 31
  const unsigned rowoff = (bq*32u+trow)*9216u + hq*96u + wq;

  const unsigned off0 = __shfl(rowoff, ln, 64);       // row ln
  const unsigned off1 = __shfl(rowoff, 16+ln, 64);    // row 16+ln
  // tc for this lane's OWN eval column (m = rt*16 + ln), used in layer 1
  float tcv[2];
  tcv[0] = __shfl(tc, ln, 64);
  tcv[1] = __shfl(tc, 16+ln, 64);
  // tc per D-row (m = rt*16 + q*4 + rr), used in the lerp epilogue
  float tcm[2][4];
  #pragma unroll
  for(int rt=0;rt<2;rt++)
    #pragma unroll
    for(int rr=0;rr<4;rr++)
      tcm[rt][rr] = __shfl(tc, rt*16 + q*4 + rr, 64);

  // ---- F fragments: per-lane F[m=ln][k=q*8+j], 2 ksteps, hi+lo ----
  s16x8 ahi[2][2], alo[2][2];
  {
    const size_t o0 = (size_t)off0*64u + (size_t)(q*8);
    const size_t o1 = (size_t)off1*64u + (size_t)(q*8);
    ahi[0][0] = *(const s16x8*)(fhi+o0);    ahi[0][1] = *(const s16x8*)(fhi+o0+32);
    ahi[1][0] = *(const s16x8*)(fhi+o1);    ahi[1][1] = *(const s16x8*)(fhi+o1+32);
    alo[0][0] = *(const s16x8*)(flo+o0);    alo[0][1] = *(const s16x8*)(flo+o0+32);
    alo[1][0] = *(const s16x8*)(flo+o1);    alo[1][1] = *(const s16x8*)(flo+o1+32);
  }

  // ---- layer 1 (swapped): D[n-within][m=ln]; lane keeps its own row ----
  // acc is in REVOLUTIONS (W1F pre-scaled); unscaled tc/bias terms fold in
  // via fmaf(SREV, fmaf(tcr,w1q,b1q), acc) — same op count as before.
  u32x4 a2w[2][8];
  const int l16 = lane*8;
  #pragma unroll
  for(int nt=0; nt<16; nt++){
    const int nb = nt<<4;
    const s16x8 bf0 = *(const s16x8*)(W1F  + (nt*2+0)*512 + l16);
    const s16x8 bf1 = *(const s16x8*)(W1F  + (nt*2+1)*512 + l16);
    const s16x8 bl0 = *(const s16x8*)(W1FL + (nt*2+0)*512 + l16);
    const s16x8 bl1 = *(const s16x8*)(W1FL + (nt*2+1)*512 + l16);
    const float4 b1q = *(const float4*)(b1 + nb + q*4);           // b1[n] (raw)
    const float4 w1q = *(const float4*)(W1 + 64*256 + nb + q*4);  // W1[64][n] (raw)
    #pragma unroll
    for(int rt=0;rt<2;rt++){
      f32x4 acc = {0.f,0.f,0.f,0.f};
      acc = __builtin_amdgcn_mfma_f32_16x16x32_bf16(bf0, ahi[rt][0], acc, 0,0,0);
      acc = __builtin_amdgcn_mfma_f32_16x16x32_bf16(bf1, ahi[rt][1], acc, 0,0,0);
      acc = __builtin_amdgcn_mfma_f32_16x16x32_bf16(bf0, alo[rt][0], acc, 0,0,0);
      acc = __builtin_amdgcn_mfma_f32_16x16x32_bf16(bf1, alo[rt][1], acc, 0,0,0);
      acc = __builtin_amdgcn_mfma_f32_16x16x32_bf16(bl0, ahi[rt][0], acc, 0,0,0);
      acc = __builtin_amdgcn_mfma_f32_16x16x32_bf16(bl1, ahi[rt][1], acc, 0,0,0);
      const float tcr = tcv[rt];
      const float s0 = sin_rev(fmaf(SREV, fmaf(tcr, w1q.x, b1q.x), acc[0]));
      const float s1 = sin_rev(fmaf(SREV, fmaf(tcr, w1q.y, b1q.y), acc[1]));
      const float s2 = sin_rev(fmaf(SREV, fmaf(tcr, w1q.z, b1q.z), acc[2]));
      const float s3 = sin_rev(fmaf(SREV, fmaf(tcr, w1q.w, b1q.w), acc[3]));
      a2w[rt][nt>>1][(nt&1)*2+0] = cvt_pk_bf16(s0,s1);
      a2w[rt][nt>>1][(nt&1)*2+1] = cvt_pk_bf16(s2,s3);
    }
  }

  // ---- layer 2 (+3 folded): h2 = sin(2pi*(acc2 + s*b2)); pred = h2@W3 ----
  float pacc[2][4];
  #pragma unroll
  for(int rt=0;rt<2;rt++)
    #pragma unroll
    for(int rr=0;rr<4;rr++) pacc[rt][rr]=0.f;

  #pragma unroll 1
  for(int cg=0; cg<4; cg++){
    f32x4 acc2[2][4];
    const f32x4 zv = {0.f,0.f,0.f,0.f};
    #pragma unroll
    for(int rt=0;rt<2;rt++)
      #pragma unroll
      for(int nt=0;nt<4;nt++) acc2[rt][nt] = zv;

    #pragma unroll
    for(int ks=0; ks<8; ks++){
      const s16x8 a20 = __builtin_bit_cast(s16x8, a2w[0][ks]);
      const s16x8 a21 = __builtin_bit_cast(s16x8, a2w[1][ks]);
      #pragma unroll
      for(int nt=0;nt<4;nt++){
        const s16x8 bfr = *(const s16x8*)(W2F + (((cg*4+nt)*8+ks)*512) + l16);
        acc2[0][nt] = __builtin_amdgcn_mfma_f32_16x16x32_bf16(a20, bfr, acc2[0][nt], 0,0,0);
        acc2[1][nt] = __builtin_amdgcn_mfma_f32_16x16x32_bf16(a21, bfr, acc2[1][nt], 0,0,0);
      }
    }
    #pragma unroll
    for(int nt=0;nt<4;nt++){
      const int n = cg*64 + nt*16 + ln;
      const float sb2 = SREV * b2[n];
      const float w3v = W3[n];
      #pragma unroll
      for(int rt=0;rt<2;rt++)
        #pragma unroll
        for(int rr=0;rr<4;rr++){
          const float h2 = sin_rev(acc2[rt][nt][rr] + sb2);
          pacc[rt][rr] += h2*w3v;
        }
    }
  }

  // reduce over the 16 n-lanes (xor within ln bits keeps q fixed)
  #pragma unroll
  for(int rt=0;rt<2;rt++)
    #pragma unroll
    for(int rr=0;rr<4;rr++){
      float v = pacc[rt][rr];
      v += __shfl_xor(v, 1, 64);
      v += __shfl_xor(v, 2, 64);
      v += __shfl_xor(v, 4, 64);
      v += __shfl_xor(v, 8, 64);
      pacc[rt][rr] = v;
    }

  // ---- fused lerp: rows (2s, 2s+1) = (floor, ceil) of one pixel ----
  if(ln==0){
    const float b3v = b3[0];
    #pragma unroll
    for(int rt=0;rt<2;rt++){
      #pragma unroll
      for(int s=0;s<2;s++){
        const int m0 = rt*16 + q*4 + 2*s;
        const float tcp = tcm[rt][2*s];
        const int tip = (int)floorf((tcp+1.0f)/dstep);
        const float fci = (float)((double)tip*(2.0/31.0) - 1.0);
        const float tau = (tcp - fci)/dstep;
        const unsigned px = (evbase + (unsigned)m0)>>1;
        out[px] = pacc[rt][2*s]*(1.0f-tau) + pacc[rt][2*s+1]*tau + b3v;
      }
    }
  }
}

extern "C" void kernel_launch(void* const* d_in, const int* in_sizes, int n_in,
                              void* d_out, int out_size, void* d_ws, size_t ws_size,
                              hipStream_t stream){
  const float* xr     = (const float*)d_in[0];
  const float* xi     = (const float*)d_in[1];
  const float* tcoord = (const float*)d_in[2];
  const float* enc_w  = (const float*)d_in[3];
  const float* enc_b  = (const float*)d_in[4];
  const float* W1     = (const float*)d_in[5];
  const float* b1     = (const float*)d_in[6];
  const float* W2     = (const float*)d_in[7];
  const float* b2     = (const float*)d_in[8];
  const float* W3     = (const float*)d_in[9];
  const float* b3     = (const float*)d_in[10];

  char* ws = (char*)d_ws;
  short* fhi  = (short*)(ws);
  short* flo  = (short*)(ws + 75497472);
  short* W1F  = (short*)(ws + 150994944);
  short* W1FL = (short*)(ws + 151027712);
  short* W2F  = (short*)(ws + 151060480);
  float* out  = (float*)d_out;

  hipLaunchKernelGGL(prep_kernel, dim3(64),   dim3(256), 0, stream, W1, W2, W1F, W1FL, W2F);
  hipLaunchKernelGGL(conv_kernel, dim3(2304), dim3(256), 0, stream, xr, xi, enc_w, enc_b, fhi, flo);
  hipLaunchKernelGGL(mlp_kernel,  dim3(9216), dim3(256), 0, stream, tcoord, fhi, flo,
                     W1F, W1FL, W1, b1, W2F, b2, W3, b3, out);
}

// Round 4
// 502.074 us; speedup vs baseline: 1.3322x; 1.3322x over previous
//
#include <hip/hip_runtime.h>

// LIIFParametric3DConv — round 16: RT=4 weight amortization (+ keep VALU diet).
// R15 post-mortem: launch_bounds(256,4) capped VGPR at 64 < ~96 needed ->
// scratch spills (WRITE_SIZE 2.3MB -> 195MB), mlp 373->466us. Registers are
// the binding resource; occupancy knob is spill-fatal here.
// R16: spend registers on TA-transaction amortization instead. Each wave now
// handles 64 evals (RT=4 row-tiles of 16), so every weight fragment load
// feeds 4 MFMAs instead of 2 -> weight cache-line transactions per eval
// halve (75M vs 132M total). bounds(256,2) = VGPR cap 256; audited peak
// ~235 (a2w[4][8]=128 + feat 64 + working). Layer-2 loops reordered
// ks-innermost so acc2 liveness is 16 regs. Canary: mlp WRITE_SIZE must
// stay ~2.3MB (no spills).
//
// ws layout (bytes):
//   fhi  @ 0          : 75,497,472  (589824 rows x 64ch bf16, hi)
//   flo  @ 75497472   : 75,497,472  (lo = bf16(f - hi))
//   W1F  @ 150994944  : 32,768      (32 frags x 1KB, fragment-ordered, x s)
//   W1FL @ 151027712  : 32,768      (lo part, x s)
//   W2F  @ 151060480  : 131,072     (128 frags x 1KB, k permuted by R(k2), x s)
//   total 151,191,552

using s16x8 = __attribute__((ext_vector_type(8))) short;
using f32x4 = __attribute__((ext_vector_type(4))) float;
using u32x4 = __attribute__((ext_vector_type(4))) unsigned int;

#define SREV 4.7746482927568600f   // 30/(2*pi)

__device__ __forceinline__ float bf2f(unsigned short u){
  return __uint_as_float(((unsigned)u) << 16);
}
__device__ __forceinline__ short f2bf(float f){
  unsigned b = __float_as_uint(f);
  return (short)((b + 0x7FFFu + ((b >> 16) & 1u)) >> 16);
}
__device__ __forceinline__ float sin_rev(float x){   // sin(2*pi*x)
  float r; asm("v_sin_f32 %0, %1" : "=v"(r) : "v"(x)); return r;
}
__device__ __forceinline__ unsigned cvt_pk_bf16(float lo, float hi){
  unsigned r; asm("v_cvt_pk_bf16_f32 %0, %1, %2" : "=v"(r) : "v"(lo), "v"(hi));
  return r;  // D[15:0]=bf16(lo), D[31:16]=bf16(hi)
}

// ---------------- prep: fragment-ordered, pre-scaled weights ----------------
// 64 blocks x 256. W1 frag f=nt*2+kk: lane l elem j -> n=nt*16+(l&15),
// k=kk*32+(l>>4)*8+j, value hi/lo bf16 of s*W1[k][n].
// W2 frag f: n=(f>>5)*64+((f>>3)&3)*16+(l&15), q=l>>4,
// R=(2*(f&7)+(j>>2))*16+q*4+(j&3); value bf16(s*W2[R][n]).
__global__ __launch_bounds__(256) void prep_kernel(
    const float* __restrict__ W1, const float* __restrict__ W2,
    short* __restrict__ W1F, short* __restrict__ W1FL, short* __restrict__ W2F){
  const int gid = blockIdx.x*256 + threadIdx.x;   // 0..16383
  {
    const int i = gid;
    const int f = i>>9;
    const int r = i&511;
    const int l = r>>3, j = r&7;
    const int nt = f>>1, kk = f&1;
    const int n = nt*16 + (l&15);
    const int k = kk*32 + (l>>4)*8 + j;
    const float w = W1[(size_t)k*256 + n] * SREV;
    const short h = f2bf(w);
    W1F[i]  = h;
    W1FL[i] = f2bf(w - bf2f((unsigned short)h));
  }
  #pragma unroll
  for(int i=gid; i<65536; i+=16384){
    const int f = i>>9;
    const int r = i&511;
    const int l = r>>3, j = r&7;
    const int ks = f&7;
    const int q  = l>>4;
    const int n  = (f>>5)*64 + ((f>>3)&3)*16 + (l&15);
    const int R  = (2*ks + (j>>2))*16 + q*4 + (j&3);
    W2F[i] = f2bf(W2[(size_t)R*256 + n] * SREV);
  }
}

// ---------------- conv3d 2->64, 3x3x3, SAME; writes hi/lo bf16 --------------
__global__ __launch_bounds__(256) void conv_kernel(
    const float* __restrict__ xr, const float* __restrict__ xi,
    const float* __restrict__ enc_w, const float* __restrict__ enc_b,
    short* __restrict__ fhi, short* __restrict__ flo)
{
  __shared__ __align__(16) float wl[64][56];
  __shared__ float bl[64];
  const int tid = threadIdx.x;
  for(int i=tid;i<3456;i+=256) wl[i/54][i%54] = enc_w[i];
  if(tid<128) wl[tid>>1][54+(tid&1)] = 0.f;
  if(tid<64)  bl[tid] = enc_b[tid];
  __syncthreads();

  const unsigned bi   = blockIdx.x;          // 2304 = 2*32*36
  const unsigned tile = bi % 36u;
  const unsigned t    = (bi/36u) % 32u;
  const unsigned b    = bi / 1152u;
  const int h = (int)((tile/6u)*16u) + (tid>>4);
  const int w = (int)((tile%6u)*16u) + (tid&15);

  float xv[56];
  xv[54]=0.f; xv[55]=0.f;
  int k=0;
  #pragma unroll
  for(int i=0;i<2;i++){
    const float* src = i ? xi : xr;
    #pragma unroll
    for(int dz=-1;dz<=1;dz++){
      const int tt = (int)t + dz;
      const bool tok = (tt>=0 && tt<32);
      const size_t tbase = (size_t)(b*32u + (unsigned)(tok?tt:0))*9216u;
      #pragma unroll
      for(int dy=-1;dy<=1;dy++){
        const int hh = h+dy;
        const bool hok = (hh>=0 && hh<96);
        #pragma unroll
        for(int dx=-1;dx<=1;dx++){
          const int ww = w+dx;
          const bool ok = tok && hok && (ww>=0 && ww<96);
          xv[k] = ok ? src[tbase + (size_t)(hh*96+ww)] : 0.f;
          k++;
        }
      }
    }
  }

  const unsigned idx = (b*32u+t)*9216u + (unsigned)(h*96+w);
  short* ph = fhi + (size_t)idx*64u;
  short* pl = flo + (size_t)idx*64u;
  #pragma unroll
  for(int g=0; g<4; g++){
    unsigned hw[8], lw[8];
    #pragma unroll
    for(int c2=0;c2<8;c2++){
      unsigned hpair=0, lpair=0;
      #pragma unroll
      for(int half=0; half<2; half++){
        const int c = g*16 + c2*2 + half;
        float acc = bl[c];
        const float4* wp = (const float4*)(&wl[c][0]);
        #pragma unroll
        for(int qq=0;qq<14;qq++){
          const float4 w4 = wp[qq];
          acc += w4.x*xv[qq*4+0] + w4.y*xv[qq*4+1]
               + w4.z*xv[qq*4+2] + w4.w*xv[qq*4+3];
        }
        const unsigned short hu = (unsigned short)f2bf(acc);
        const unsigned short lu = (unsigned short)f2bf(acc - bf2f(hu));
        hpair |= ((unsigned)hu) << (16*half);
        lpair |= ((unsigned)lu) << (16*half);
      }
      hw[c2]=hpair; lw[c2]=lpair;
    }
    uint4* dh = (uint4*)(ph + g*16);
    uint4* dl = (uint4*)(pl + g*16);
    dh[0] = make_uint4(hw[0],hw[1],hw[2],hw[3]);
    dh[1] = make_uint4(hw[4],hw[5],hw[6],hw[7]);
    dl[0] = make_uint4(lw[0],lw[1],lw[2],lw[3]);
    dl[1] = make_uint4(lw[4],lw[5],lw[6],lw[7]);
  }
}

// ---------------- fused SIREN MLP + lerp, MFMA 16x16x32 bf16, RT=4 ----------
// Block: 4 waves x 64 evals. No LDS, no barriers. Weight loads fragment-
// ordered (base + f*1024 + lane*16, coalesced) and amortized over 4 row-tiles.
__global__ __launch_bounds__(256, 2) void mlp_kernel(
  const float* __restrict__ tcoord,
  const short* __restrict__ fhi, const short* __restrict__ flo,
  const short* __restrict__ W1F, const short* __restrict__ W1FL,
  const float* __restrict__ W1,  const float* __restrict__ b1,
  const short* __restrict__ W2F, const float* __restrict__ b2,
  const float* __restrict__ W3,  const float* __restrict__ b3,
  float* __restrict__ out)
{
  const int tid  = threadIdx.x;
  const int wave = tid>>6;
  const int lane = tid&63;
  const int q  = lane>>4;   // quad
  const int ln = lane&15;
  const unsigned evbase = blockIdx.x*256u + (unsigned)wave*64u;

  // ---- per-lane meta for eval (evbase + lane) ----
  const unsigned ev = evbase + (unsigned)lane;
  const unsigned pt = ev>>1;
  const unsigned fc = ev&1u;
  const unsigned wq = pt%96u;
  const unsigned hq = (pt/96u)%96u;
  const unsigned jq = (pt/9216u)%32u;
  const unsigned bq = pt/294912u;
  float tc = tcoord[bq*32u+jq];
  tc = fminf(fmaxf(tc, -1.0f), 1.0f - 1e-6f);
  const float dstep = 2.0f/31.0f;
  const int ti = (int)floorf((tc+1.0f)/dstep);
  const unsigned trow = (unsigned)ti + fc;       // <= 31
  const unsigned rowoff = (bq*32u+trow)*9216u + hq*96u + wq;

  // per row-tile rt: feature row offset + own-eval tc
  float tcv[4];
  s16x8 ahi[4][2], alo[4][2];
  #pragma unroll
  for(int rt=0;rt<4;rt++){
    const unsigned offr = __shfl(rowoff, rt*16 + ln, 64);
    tcv[rt] = __shfl(tc, rt*16 + ln, 64);
    const size_t o = (size_t)offr*64u + (size_t)(q*8);
    ahi[rt][0] = *(const s16x8*)(fhi+o);  ahi[rt][1] = *(const s16x8*)(fhi+o+32);
    alo[rt][0] = *(const s16x8*)(flo+o);  alo[rt][1] = *(const s16x8*)(flo+o+32);
  }

  // ---- layer 1 (swapped): lane keeps h1 of its own eval row ----
  // Slot (nt,q,rr) -> h1[n=nt*16+q*4+rr] of eval m = rt*16+ln. Packed so
  // a2w[rt][ks] IS the layer-2 A-fragment (W2F rows pre-permuted by R(k2)).
  u32x4 a2w[4][8];
  const int l16 = lane*8;
  #pragma unroll
  for(int nt=0; nt<16; nt++){
    const int nb = nt<<4;
    const s16x8 bf0 = *(const s16x8*)(W1F  + (nt*2+0)*512 + l16);
    const s16x8 bf1 = *(const s16x8*)(W1F  + (nt*2+1)*512 + l16);
    const s16x8 bl0 = *(const s16x8*)(W1FL + (nt*2+0)*512 + l16);
    const s16x8 bl1 = *(const s16x8*)(W1FL + (nt*2+1)*512 + l16);
    const float4 b1q = *(const float4*)(b1 + nb + q*4);           // b1[n] (raw)
    const float4 w1q = *(const float4*)(W1 + 64*256 + nb + q*4);  // W1[64][n] (raw)
    #pragma unroll
    for(int rt=0;rt<4;rt++){
      f32x4 acc = {0.f,0.f,0.f,0.f};
      acc = __builtin_amdgcn_mfma_f32_16x16x32_bf16(bf0, ahi[rt][0], acc, 0,0,0);
      acc = __builtin_amdgcn_mfma_f32_16x16x32_bf16(bf1, ahi[rt][1], acc, 0,0,0);
      acc = __builtin_amdgcn_mfma_f32_16x16x32_bf16(bf0, alo[rt][0], acc, 0,0,0);
      acc = __builtin_amdgcn_mfma_f32_16x16x32_bf16(bf1, alo[rt][1], acc, 0,0,0);
      acc = __builtin_amdgcn_mfma_f32_16x16x32_bf16(bl0, ahi[rt][0], acc, 0,0,0);
      acc = __builtin_amdgcn_mfma_f32_16x16x32_bf16(bl1, ahi[rt][1], acc, 0,0,0);
      const float tcr = tcv[rt];
      const float s0 = sin_rev(fmaf(SREV, fmaf(tcr, w1q.x, b1q.x), acc[0]));
      const float s1 = sin_rev(fmaf(SREV, fmaf(tcr, w1q.y, b1q.y), acc[1]));
      const float s2 = sin_rev(fmaf(SREV, fmaf(tcr, w1q.z, b1q.z), acc[2]));
      const float s3 = sin_rev(fmaf(SREV, fmaf(tcr, w1q.w, b1q.w), acc[3]));
      a2w[rt][nt>>1][(nt&1)*2+0] = cvt_pk_bf16(s0,s1);
      a2w[rt][nt>>1][(nt&1)*2+1] = cvt_pk_bf16(s2,s3);
    }
  }

  // ---- layer 2 (+3 folded): ks-innermost so acc2 liveness is 16 regs ----
  float pacc[4][4];
  #pragma unroll
  for(int rt=0;rt<4;rt++)
    #pragma unroll
    for(int rr=0;rr<4;rr++) pacc[rt][rr]=0.f;

  #pragma unroll 1
  for(int cg=0; cg<4; cg++){
    #pragma unroll
    for(int nt=0;nt<4;nt++){
      f32x4 acc2[4];
      const f32x4 zv = {0.f,0.f,0.f,0.f};
      #pragma unroll
      for(int rt=0;rt<4;rt++) acc2[rt] = zv;
      #pragma unroll
      for(int ks=0; ks<8; ks++){
        const s16x8 bfr = *(const s16x8*)(W2F + (((cg*4+nt)*8+ks)*512) + l16);
        #pragma unroll
        for(int rt=0;rt<4;rt++){
          const s16x8 a2 = __builtin_bit_cast(s16x8, a2w[rt][ks]);
          acc2[rt] = __builtin_amdgcn_mfma_f32_16x16x32_bf16(a2, bfr, acc2[rt], 0,0,0);
        }
      }
      const int n = cg*64 + nt*16 + ln;
      const float sb2 = SREV * b2[n];
      const float w3v = W3[n];
      #pragma unroll
      for(int rt=0;rt<4;rt++)
        #pragma unroll
        for(int rr=0;rr<4;rr++){
          const float h2 = sin_rev(acc2[rt][rr] + sb2);
          pacc[rt][rr] += h2*w3v;
        }
    }
  }

  // reduce over the 16 n-lanes (xor within ln bits keeps q fixed)
  #pragma unroll
  for(int rt=0;rt<4;rt++)
    #pragma unroll
    for(int rr=0;rr<4;rr++){
      float v = pacc[rt][rr];
      v += __shfl_xor(v, 1, 64);
      v += __shfl_xor(v, 2, 64);
      v += __shfl_xor(v, 4, 64);
      v += __shfl_xor(v, 8, 64);
      pacc[rt][rr] = v;
    }

  // ---- fused lerp: rows (2s, 2s+1) = (floor, ceil) of one pixel ----
  float tcp_[4][2];
  #pragma unroll
  for(int rt=0;rt<4;rt++)
    #pragma unroll
    for(int s=0;s<2;s++)
      tcp_[rt][s] = __shfl(tc, rt*16 + q*4 + 2*s, 64);

  if(ln==0){
    const float b3v = b3[0];
    #pragma unroll
    for(int rt=0;rt<4;rt++){
      #pragma unroll
      for(int s=0;s<2;s++){
        const int m0 = rt*16 + q*4 + 2*s;
        const float tcp = tcp_[rt][s];
        const int tip = (int)floorf((tcp+1.0f)/dstep);
        const float fci = (float)((double)tip*(2.0/31.0) - 1.0);
        const float tau = (tcp - fci)/dstep;
        const unsigned px = (evbase + (unsigned)m0)>>1;
        out[px] = pacc[rt][2*s]*(1.0f-tau) + pacc[rt][2*s+1]*tau + b3v;
      }
    }
  }
}

extern "C" void kernel_launch(void* const* d_in, const int* in_sizes, int n_in,
                              void* d_out, int out_size, void* d_ws, size_t ws_size,
                              hipStream_t stream){
  const float* xr     = (const float*)d_in[0];
  const float* xi     = (const float*)d_in[1];
  const float* tcoord = (const float*)d_in[2];
  const float* enc_w  = (const float*)d_in[3];
  const float* enc_b  = (const float*)d_in[4];
  const float* W1     = (const float*)d_in[5];
  const float* b1     = (const float*)d_in[6];
  const float* W2     = (const float*)d_in[7];
  const float* b2     = (const float*)d_in[8];
  const float* W3     = (const float*)d_in[9];
  const float* b3     = (const float*)d_in[10];

  char* ws = (char*)d_ws;
  short* fhi  = (short*)(ws);
  short* flo  = (short*)(ws + 75497472);
  short* W1F  = (short*)(ws + 150994944);
  short* W1FL = (short*)(ws + 151027712);
  short* W2F  = (short*)(ws + 151060480);
  float* out  = (float*)d_out;

  hipLaunchKernelGGL(prep_kernel, dim3(64),   dim3(256), 0, stream, W1, W2, W1F, W1FL, W2F);
  hipLaunchKernelGGL(conv_kernel, dim3(2304), dim3(256), 0, stream, xr, xi, enc_w, enc_b, fhi, flo);
  hipLaunchKernelGGL(mlp_kernel,  dim3(4608), dim3(256), 0, stream, tcoord, fhi, flo,
                     W1F, W1FL, W1, b1, W2F, b2, W3, b3, out);
}

// Round 5
// 412.976 us; speedup vs baseline: 1.6196x; 1.2157x over previous
//
#include <hip/hip_runtime.h>

// LIIFParametric3DConv — round 17: MFMA conv (im2col GEMM), mlp untouched.
// R16 post-mortem: mlp 296us (matched prediction); total-mlp gap stable
// ~206us across rounds and invisible in top-5 (all slots = mlp iters).
// Theory: gap = conv + fixed overhead. This round makes conv fast by
// construction to read the gap delta: conv becomes a 16x16x32 bf16 MFMA
// GEMM (im2col K=54 pad 64, swapped operands exactly like mlp layer-1:
// lane ends with its own pixel's channels). 3-product hi/lo split keeps
// ~fp32 accuracy. Input tile in LDS (6 planes x 18x20 + zero pad); im2col
// k->offset via 64-entry LDS table, k>=54 points into the zeroed pad.
// hi/lo split = trunc-hi (exact cvt_pk) + RNE-lo: 3 VALU/value.
// Predicted: mlp rows unchanged; total 502 -> ~400 if conv was ~150us,
// ~unchanged if the gap is harness overhead.
//
// ws layout (bytes):
//   fhi  @ 0          : 75,497,472  (589824 rows x 64ch bf16, hi)
//   flo  @ 75497472   : 75,497,472  (lo = f - hi, bf16)
//   W1F  @ 150994944  : 32,768      (32 frags x 1KB, fragment-ordered, x s)
//   W1FL @ 151027712  : 32,768      (lo part, x s)
//   W2F  @ 151060480  : 131,072     (128 frags x 1KB, k permuted by R(k2), x s)
//   total 151,191,552

using s16x8 = __attribute__((ext_vector_type(8))) short;
using f32x4 = __attribute__((ext_vector_type(4))) float;
using u32x4 = __attribute__((ext_vector_type(4))) unsigned int;

#define SREV 4.7746482927568600f   // 30/(2*pi)

__device__ __forceinline__ float bf2f(unsigned short u){
  return __uint_as_float(((unsigned)u) << 16);
}
__device__ __forceinline__ short f2bf(float f){
  unsigned b = __float_as_uint(f);
  return (short)((b + 0x7FFFu + ((b >> 16) & 1u)) >> 16);
}
__device__ __forceinline__ float sin_rev(float x){   // sin(2*pi*x)
  float r; asm("v_sin_f32 %0, %1" : "=v"(r) : "v"(x)); return r;
}
__device__ __forceinline__ unsigned cvt_pk_bf16(float lo, float hi){
  unsigned r; asm("v_cvt_pk_bf16_f32 %0, %1, %2" : "=v"(r) : "v"(lo), "v"(hi));
  return r;  // D[15:0]=bf16(lo), D[31:16]=bf16(hi)
}
__device__ __forceinline__ float trunc_hi(float v){  // mantissa-truncated hi part
  return __uint_as_float(__float_as_uint(v) & 0xFFFF0000u);
}

// ---------------- prep: fragment-ordered, pre-scaled MLP weights ------------
__global__ __launch_bounds__(256) void prep_kernel(
    const float* __restrict__ W1, const float* __restrict__ W2,
    short* __restrict__ W1F, short* __restrict__ W1FL, short* __restrict__ W2F){
  const int gid = blockIdx.x*256 + threadIdx.x;   // 0..16383
  {
    const int i = gid;
    const int f = i>>9;
    const int r = i&511;
    const int l = r>>3, j = r&7;
    const int nt = f>>1, kk = f&1;
    const int n = nt*16 + (l&15);
    const int k = kk*32 + (l>>4)*8 + j;
    const float w = W1[(size_t)k*256 + n] * SREV;
    const short h = f2bf(w);
    W1F[i]  = h;
    W1FL[i] = f2bf(w - bf2f((unsigned short)h));
  }
  #pragma unroll
  for(int i=gid; i<65536; i+=16384){
    const int f = i>>9;
    const int r = i&511;
    const int l = r>>3, j = r&7;
    const int ks = f&7;
    const int q  = l>>4;
    const int n  = (f>>5)*64 + ((f>>3)&3)*16 + (l&15);
    const int R  = (2*ks + (j>>2))*16 + q*4 + (j&3);
    W2F[i] = f2bf(W2[(size_t)R*256 + n] * SREV);
  }
}

// ---------------- conv3d 2->64 via MFMA im2col GEMM -------------------------
// Block = one 16x16 spatial tile at (b,t). Wave w owns rows 4w..4w+3 (rt),
// lane ln = col. Swapped MFMA: A = conv weights [row=ln->channel, k=q*8+j],
// B = im2col features [col=ln->pixel, k=q*8+j]; D: lane holds channels
// nt*16+q*4+rr of its pixel -> trunc/RNE split -> uint2 stores.
__global__ __launch_bounds__(256) void conv_kernel(
    const float* __restrict__ xr, const float* __restrict__ xi,
    const float* __restrict__ enc_w, const float* __restrict__ enc_b,
    short* __restrict__ fhi, short* __restrict__ flo)
{
  // 6 planes (i*3+dz) x 18 rows x 20 cols f32 = 2160 dwords, + zeroed pad
  // (sentinel reads land in [2160, 2160+315] < 2560). offs: k -> dword offset.
  __shared__ __align__(16) float sm[2560];
  __shared__ __align__(16) int offs[64];
  const int tid  = threadIdx.x;
  const int wave = tid>>6;
  const int lane = tid&63;
  const int q  = lane>>4;
  const int ln = lane&15;

  // phase 1: zero tile+pad, build k->offset table
  #pragma unroll
  for(int z=0; z<10; z++) sm[tid + z*256] = 0.f;
  if(tid < 64){
    int off = 2160;                       // sentinel: zeroed pad
    if(tid < 54){
      const int i  = (tid >= 27) ? 1 : 0;
      const int kk = tid - i*27;
      const int dz = kk/9;
      const int rem = kk - dz*9;
      const int dy = rem/3;
      const int dx = rem - dy*3;
      off = ((i*3+dz)*18 + dy)*20 + dx;
    }
    offs[tid] = off;
  }
  __syncthreads();

  // phase 2: stage input tile (18x18 valid region per plane, halo stays 0)
  const unsigned bi   = blockIdx.x;          // 2304 = 2*32*36
  const unsigned tile = bi % 36u;
  const unsigned t    = (bi/36u) % 32u;
  const unsigned b    = bi / 1152u;
  const int h0 = (int)((tile/6u)*16u);
  const int w0 = (int)((tile%6u)*16u);
  #pragma unroll
  for(int i=0;i<2;i++){
    const float* src = i ? xi : xr;
    #pragma unroll
    for(int dz=0;dz<3;dz++){
      const int tt = (int)t + dz - 1;
      if(tt >= 0 && tt < 32){
        const float* sp = src + (size_t)(b*32u + (unsigned)tt)*9216u;
        float* dp = sm + (i*3+dz)*360;
        for(int e = tid; e < 324; e += 256){
          const int r = e/18, c = e - r*18;
          const int hh = h0-1+r, ww = w0-1+c;
          if(hh>=0 && hh<96 && ww>=0 && ww<96)
            dp[r*20 + c] = sp[hh*96 + ww];
        }
      }
    }
  }
  __syncthreads();

  // conv-weight A-fragments from global (L2-hot, 13.8KB), trunc/RNE hi-lo
  s16x8 wh[8], wl[8];
  #pragma unroll
  for(int f=0; f<8; f++){
    const int nt = f>>1, ks = f&1;
    const int n  = nt*16 + ln;
    const int k0 = ks*32 + q*8;
    unsigned hp[4], lp[4];
    #pragma unroll
    for(int jp=0; jp<4; jp++){
      const int ka = k0 + jp*2, kb = ka + 1;
      const float v0 = (ka < 54) ? enc_w[n*54 + ka] : 0.f;
      const float v1 = (kb < 54) ? enc_w[n*54 + kb] : 0.f;
      const float a0 = trunc_hi(v0), a1 = trunc_hi(v1);
      hp[jp] = cvt_pk_bf16(a0, a1);
      lp[jp] = cvt_pk_bf16(v0 - a0, v1 - a1);
    }
    u32x4 hv = {hp[0],hp[1],hp[2],hp[3]};
    u32x4 lv = {lp[0],lp[1],lp[2],lp[3]};
    wh[f] = __builtin_bit_cast(s16x8, hv);
    wl[f] = __builtin_bit_cast(s16x8, lv);
  }

  // per-lane im2col offsets (8 consecutive k per (ks,q)) and bias
  int4 of0a = *(const int4*)(offs + 0*32 + q*8);
  int4 of0b = *(const int4*)(offs + 0*32 + q*8 + 4);
  int4 of1a = *(const int4*)(offs + 1*32 + q*8);
  int4 of1b = *(const int4*)(offs + 1*32 + q*8 + 4);
  int ofv[16] = {of0a.x,of0a.y,of0a.z,of0a.w, of0b.x,of0b.y,of0b.z,of0b.w,
                 of1a.x,of1a.y,of1a.z,of1a.w, of1b.x,of1b.y,of1b.z,of1b.w};
  float4 bq[4];
  #pragma unroll
  for(int nt=0;nt<4;nt++) bq[nt] = *(const float4*)(enc_b + nt*16 + q*4);

  const unsigned rowbase = (b*32u+t)*9216u + (unsigned)(h0*96 + w0);

  #pragma unroll
  for(int rt=0; rt<4; rt++){
    const int R  = wave*4 + rt;
    const int pb = R*20 + ln;                 // pixel base (dwords) in plane space
    // gather im2col features, split hi/lo
    s16x8 bh[2], bl[2];
    #pragma unroll
    for(int ks=0; ks<2; ks++){
      unsigned hp[4], lp[4];
      #pragma unroll
      for(int jp=0; jp<4; jp++){
        const float v0 = sm[pb + ofv[ks*8 + jp*2 + 0]];
        const float v1 = sm[pb + ofv[ks*8 + jp*2 + 1]];
        const float a0 = trunc_hi(v0), a1 = trunc_hi(v1);
        hp[jp] = cvt_pk_bf16(a0, a1);
        lp[jp] = cvt_pk_bf16(v0 - a0, v1 - a1);
      }
      u32x4 hv = {hp[0],hp[1],hp[2],hp[3]};
      u32x4 lv = {lp[0],lp[1],lp[2],lp[3]};
      bh[ks] = __builtin_bit_cast(s16x8, hv);
      bl[ks] = __builtin_bit_cast(s16x8, lv);
    }
    const size_t pgi = (size_t)(rowbase + (unsigned)(R*96 + ln));
    #pragma unroll
    for(int nt=0; nt<4; nt++){
      f32x4 acc = {0.f,0.f,0.f,0.f};
      #pragma unroll
      for(int ks=0; ks<2; ks++){
        acc = __builtin_amdgcn_mfma_f32_16x16x32_bf16(wh[nt*2+ks], bh[ks], acc, 0,0,0);
        acc = __builtin_amdgcn_mfma_f32_16x16x32_bf16(wh[nt*2+ks], bl[ks], acc, 0,0,0);
        acc = __builtin_amdgcn_mfma_f32_16x16x32_bf16(wl[nt*2+ks], bh[ks], acc, 0,0,0);
      }
      const float v0 = acc[0] + bq[nt].x;
      const float v1 = acc[1] + bq[nt].y;
      const float v2 = acc[2] + bq[nt].z;
      const float v3 = acc[3] + bq[nt].w;
      const float a0 = trunc_hi(v0), a1 = trunc_hi(v1);
      const float a2 = trunc_hi(v2), a3 = trunc_hi(v3);
      const unsigned h01 = cvt_pk_bf16(a0, a1);
      const unsigned h23 = cvt_pk_bf16(a2, a3);
      const unsigned l01 = cvt_pk_bf16(v0 - a0, v1 - a1);
      const unsigned l23 = cvt_pk_bf16(v2 - a2, v3 - a3);
      *(uint2*)(fhi + pgi*64u + (unsigned)(nt*16 + q*4)) = make_uint2(h01, h23);
      *(uint2*)(flo + pgi*64u + (unsigned)(nt*16 + q*4)) = make_uint2(l01, l23);
    }
  }
}

// ---------------- fused SIREN MLP + lerp, MFMA 16x16x32 bf16, RT=4 ----------
// (unchanged from R16: 296us, MfmaUtil 41%, no spills)
__global__ __launch_bounds__(256, 2) void mlp_kernel(
  const float* __restrict__ tcoord,
  const short* __restrict__ fhi, const short* __restrict__ flo,
  const short* __restrict__ W1F, const short* __restrict__ W1FL,
  const float* __restrict__ W1,  const float* __restrict__ b1,
  const short* __restrict__ W2F, const float* __restrict__ b2,
  const float* __restrict__ W3,  const float* __restrict__ b3,
  float* __restrict__ out)
{
  const int tid  = threadIdx.x;
  const int wave = tid>>6;
  const int lane = tid&63;
  const int q  = lane>>4;   // quad
  const int ln = lane&15;
  const unsigned evbase = blockIdx.x*256u + (unsigned)wave*64u;

  // ---- per-lane meta for eval (evbase + lane) ----
  const unsigned ev = evbase + (unsigned)lane;
  const unsigned pt = ev>>1;
  const unsigned fc = ev&1u;
  const unsigned wq = pt%96u;
  const unsigned hq = (pt/96u)%96u;
  const unsigned jq = (pt/9216u)%32u;
  const unsigned bq = pt/294912u;
  float tc = tcoord[bq*32u+jq];
  tc = fminf(fmaxf(tc, -1.0f), 1.0f - 1e-6f);
  const float dstep = 2.0f/31.0f;
  const int ti = (int)floorf((tc+1.0f)/dstep);
  const unsigned trow = (unsigned)ti + fc;       // <= 31
  const unsigned rowoff = (bq*32u+trow)*9216u + hq*96u + wq;

  // per row-tile rt: feature row offset + own-eval tc
  float tcv[4];
  s16x8 ahi[4][2], alo[4][2];
  #pragma unroll
  for(int rt=0;rt<4;rt++){
    const unsigned offr = __shfl(rowoff, rt*16 + ln, 64);
    tcv[rt] = __shfl(tc, rt*16 + ln, 64);
    const size_t o = (size_t)offr*64u + (size_t)(q*8);
    ahi[rt][0] = *(const s16x8*)(fhi+o);  ahi[rt][1] = *(const s16x8*)(fhi+o+32);
    alo[rt][0] = *(const s16x8*)(flo+o);  alo[rt][1] = *(const s16x8*)(flo+o+32);
  }

  // ---- layer 1 (swapped): lane keeps h1 of its own eval row ----
  u32x4 a2w[4][8];
  const int l16 = lane*8;
  #pragma unroll
  for(int nt=0; nt<16; nt++){
    const int nb = nt<<4;
    const s16x8 bf0 = *(const s16x8*)(W1F  + (nt*2+0)*512 + l16);
    const s16x8 bf1 = *(const s16x8*)(W1F  + (nt*2+1)*512 + l16);
    const s16x8 bl0 = *(const s16x8*)(W1FL + (nt*2+0)*512 + l16);
    const s16x8 bl1 = *(const s16x8*)(W1FL + (nt*2+1)*512 + l16);
    const float4 b1q = *(const float4*)(b1 + nb + q*4);           // b1[n] (raw)
    const float4 w1q = *(const float4*)(W1 + 64*256 + nb + q*4);  // W1[64][n] (raw)
    #pragma unroll
    for(int rt=0;rt<4;rt++){
      f32x4 acc = {0.f,0.f,0.f,0.f};
      acc = __builtin_amdgcn_mfma_f32_16x16x32_bf16(bf0, ahi[rt][0], acc, 0,0,0);
      acc = __builtin_amdgcn_mfma_f32_16x16x32_bf16(bf1, ahi[rt][1], acc, 0,0,0);
      acc = __builtin_amdgcn_mfma_f32_16x16x32_bf16(bf0, alo[rt][0], acc, 0,0,0);
      acc = __builtin_amdgcn_mfma_f32_16x16x32_bf16(bf1, alo[rt][1], acc, 0,0,0);
      acc = __builtin_amdgcn_mfma_f32_16x16x32_bf16(bl0, ahi[rt][0], acc, 0,0,0);
      acc = __builtin_amdgcn_mfma_f32_16x16x32_bf16(bl1, ahi[rt][1], acc, 0,0,0);
      const float tcr = tcv[rt];
      const float s0 = sin_rev(fmaf(SREV, fmaf(tcr, w1q.x, b1q.x), acc[0]));
      const float s1 = sin_rev(fmaf(SREV, fmaf(tcr, w1q.y, b1q.y), acc[1]));
      const float s2 = sin_rev(fmaf(SREV, fmaf(tcr, w1q.z, b1q.z), acc[2]));
      const float s3 = sin_rev(fmaf(SREV, fmaf(tcr, w1q.w, b1q.w), acc[3]));
      a2w[rt][nt>>1][(nt&1)*2+0] = cvt_pk_bf16(s0,s1);
      a2w[rt][nt>>1][(nt&1)*2+1] = cvt_pk_bf16(s2,s3);
    }
  }

  // ---- layer 2 (+3 folded): ks-innermost so acc2 liveness is 16 regs ----
  float pacc[4][4];
  #pragma unroll
  for(int rt=0;rt<4;rt++)
    #pragma unroll
    for(int rr=0;rr<4;rr++) pacc[rt][rr]=0.f;

  #pragma unroll 1
  for(int cg=0; cg<4; cg++){
    #pragma unroll
    for(int nt=0;nt<4;nt++){
      f32x4 acc2[4];
      const f32x4 zv = {0.f,0.f,0.f,0.f};
      #pragma unroll
      for(int rt=0;rt<4;rt++) acc2[rt] = zv;
      #pragma unroll
      for(int ks=0; ks<8; ks++){
        const s16x8 bfr = *(const s16x8*)(W2F + (((cg*4+nt)*8+ks)*512) + l16);
        #pragma unroll
        for(int rt=0;rt<4;rt++){
          const s16x8 a2 = __builtin_bit_cast(s16x8, a2w[rt][ks]);
          acc2[rt] = __builtin_amdgcn_mfma_f32_16x16x32_bf16(a2, bfr, acc2[rt], 0,0,0);
        }
      }
      const int n = cg*64 + nt*16 + ln;
      const float sb2 = SREV * b2[n];
      const float w3v = W3[n];
      #pragma unroll
      for(int rt=0;rt<4;rt++)
        #pragma unroll
        for(int rr=0;rr<4;rr++){
          const float h2 = sin_rev(acc2[rt][rr] + sb2);
          pacc[rt][rr] += h2*w3v;
        }
    }
  }

  // reduce over the 16 n-lanes (xor within ln bits keeps q fixed)
  #pragma unroll
  for(int rt=0;rt<4;rt++)
    #pragma unroll
    for(int rr=0;rr<4;rr++){
      float v = pacc[rt][rr];
      v += __shfl_xor(v, 1, 64);
      v += __shfl_xor(v, 2, 64);
      v += __shfl_xor(v, 4, 64);
      v += __shfl_xor(v, 8, 64);
      pacc[rt][rr] = v;
    }

  // ---- fused lerp: rows (2s, 2s+1) = (floor, ceil) of one pixel ----
  float tcp_[4][2];
  #pragma unroll
  for(int rt=0;rt<4;rt++)
    #pragma unroll
    for(int s=0;s<2;s++)
      tcp_[rt][s] = __shfl(tc, rt*16 + q*4 + 2*s, 64);

  if(ln==0){
    const float b3v = b3[0];
    #pragma unroll
    for(int rt=0;rt<4;rt++){
      #pragma unroll
      for(int s=0;s<2;s++){
        const int m0 = rt*16 + q*4 + 2*s;
        const float tcp = tcp_[rt][s];
        const int tip = (int)floorf((tcp+1.0f)/dstep);
        const float fci = (float)((double)tip*(2.0/31.0) - 1.0);
        const float tau = (tcp - fci)/dstep;
        const unsigned px = (evbase + (unsigned)m0)>>1;
        out[px] = pacc[rt][2*s]*(1.0f-tau) + pacc[rt][2*s+1]*tau + b3v;
      }
    }
  }
}

extern "C" void kernel_launch(void* const* d_in, const int* in_sizes, int n_in,
                              void* d_out, int out_size, void* d_ws, size_t ws_size,
                              hipStream_t stream){
  const float* xr     = (const float*)d_in[0];
  const float* xi     = (const float*)d_in[1];
  const float* tcoord = (const float*)d_in[2];
  const float* enc_w  = (const float*)d_in[3];
  const float* enc_b  = (const float*)d_in[4];
  const float* W1     = (const float*)d_in[5];
  const float* b1     = (const float*)d_in[6];
  const float* W2     = (const float*)d_in[7];
  const float* b2     = (const float*)d_in[8];
  const float* W3     = (const float*)d_in[9];
  const float* b3     = (const float*)d_in[10];

  char* ws = (char*)d_ws;
  short* fhi  = (short*)(ws);
  short* flo  = (short*)(ws + 75497472);
  short* W1F  = (short*)(ws + 150994944);
  short* W1FL = (short*)(ws + 151027712);
  short* W2F  = (short*)(ws + 151060480);
  float* out  = (float*)d_out;

  hipLaunchKernelGGL(prep_kernel, dim3(64),   dim3(256), 0, stream, W1, W2, W1F, W1FL, W2F);
  hipLaunchKernelGGL(conv_kernel, dim3(2304), dim3(256), 0, stream, xr, xi, enc_w, enc_b, fhi, flo);
  hipLaunchKernelGGL(mlp_kernel,  dim3(4608), dim3(256), 0, stream, tcoord, fhi, flo,
                     W1F, W1FL, W1, b1, W2F, b2, W3, b3, out);
}

// Round 6
// 394.282 us; speedup vs baseline: 1.6964x; 1.0474x over previous
//
#include <hip/hip_runtime.h>

// LIIFParametric3DConv — round 18: LDS-staged MLP weights + setprio.
// R17 post-mortem: conv fixed (gap 206->113us), mlp unchanged at 300us with
// MfmaUtil 40% + VALUBusy 39% ~= 80% serial, ~20% stall. Theory: weight
// streams from L2 (3072 lines/wave TA + exposed latency) stall waves and
// prevent cross-wave MFMA/VALU overlap at 2 waves/SIMD.
// R18: stage W1F+W1FL (64KB) in LDS once; stage W2F per-cg (32KB) double-
// buffered in the same 64KB; all weight reads become conflict-free
// ds_read_b128. s_setprio(1) around MFMA clusters (T5). LDS = exactly 64KB
// -> 2 blocks/CU preserved. mlp math identical (absmax unchanged).
//
// ws layout (bytes):
//   fhi  @ 0          : 75,497,472  (589824 rows x 64ch bf16, hi)
//   flo  @ 75497472   : 75,497,472  (lo = f - hi, bf16)
//   W1F  @ 150994944  : 32,768      (32 frags x 1KB, fragment-ordered, x s)
//   W1FL @ 151027712  : 32,768      (lo part, x s)
//   W2F  @ 151060480  : 131,072     (128 frags x 1KB, k permuted by R(k2), x s)
//   total 151,191,552

using s16x8 = __attribute__((ext_vector_type(8))) short;
using f32x4 = __attribute__((ext_vector_type(4))) float;
using u32x4 = __attribute__((ext_vector_type(4))) unsigned int;

#define SREV 4.7746482927568600f   // 30/(2*pi)

__device__ __forceinline__ float bf2f(unsigned short u){
  return __uint_as_float(((unsigned)u) << 16);
}
__device__ __forceinline__ short f2bf(float f){
  unsigned b = __float_as_uint(f);
  return (short)((b + 0x7FFFu + ((b >> 16) & 1u)) >> 16);
}
__device__ __forceinline__ float sin_rev(float x){   // sin(2*pi*x)
  float r; asm("v_sin_f32 %0, %1" : "=v"(r) : "v"(x)); return r;
}
__device__ __forceinline__ unsigned cvt_pk_bf16(float lo, float hi){
  unsigned r; asm("v_cvt_pk_bf16_f32 %0, %1, %2" : "=v"(r) : "v"(lo), "v"(hi));
  return r;  // D[15:0]=bf16(lo), D[31:16]=bf16(hi)
}
__device__ __forceinline__ float trunc_hi(float v){  // mantissa-truncated hi part
  return __uint_as_float(__float_as_uint(v) & 0xFFFF0000u);
}

// ---------------- prep: fragment-ordered, pre-scaled MLP weights ------------
__global__ __launch_bounds__(256) void prep_kernel(
    const float* __restrict__ W1, const float* __restrict__ W2,
    short* __restrict__ W1F, short* __restrict__ W1FL, short* __restrict__ W2F){
  const int gid = blockIdx.x*256 + threadIdx.x;   // 0..16383
  {
    const int i = gid;
    const int f = i>>9;
    const int r = i&511;
    const int l = r>>3, j = r&7;
    const int nt = f>>1, kk = f&1;
    const int n = nt*16 + (l&15);
    const int k = kk*32 + (l>>4)*8 + j;
    const float w = W1[(size_t)k*256 + n] * SREV;
    const short h = f2bf(w);
    W1F[i]  = h;
    W1FL[i] = f2bf(w - bf2f((unsigned short)h));
  }
  #pragma unroll
  for(int i=gid; i<65536; i+=16384){
    const int f = i>>9;
    const int r = i&511;
    const int l = r>>3, j = r&7;
    const int ks = f&7;
    const int q  = l>>4;
    const int n  = (f>>5)*64 + ((f>>3)&3)*16 + (l&15);
    const int R  = (2*ks + (j>>2))*16 + q*4 + (j&3);
    W2F[i] = f2bf(W2[(size_t)R*256 + n] * SREV);
  }
}

// ---------------- conv3d 2->64 via MFMA im2col GEMM (unchanged, ~40us) ------
__global__ __launch_bounds__(256) void conv_kernel(
    const float* __restrict__ xr, const float* __restrict__ xi,
    const float* __restrict__ enc_w, const float* __restrict__ enc_b,
    short* __restrict__ fhi, short* __restrict__ flo)
{
  __shared__ __align__(16) float sm[2560];
  __shared__ __align__(16) int offs[64];
  const int tid  = threadIdx.x;
  const int wave = tid>>6;
  const int lane = tid&63;
  const int q  = lane>>4;
  const int ln = lane&15;

  #pragma unroll
  for(int z=0; z<10; z++) sm[tid + z*256] = 0.f;
  if(tid < 64){
    int off = 2160;                       // sentinel: zeroed pad
    if(tid < 54){
      const int i  = (tid >= 27) ? 1 : 0;
      const int kk = tid - i*27;
      const int dz = kk/9;
      const int rem = kk - dz*9;
      const int dy = rem/3;
      const int dx = rem - dy*3;
      off = ((i*3+dz)*18 + dy)*20 + dx;
    }
    offs[tid] = off;
  }
  __syncthreads();

  const unsigned bi   = blockIdx.x;          // 2304 = 2*32*36
  const unsigned tile = bi % 36u;
  const unsigned t    = (bi/36u) % 32u;
  const unsigned b    = bi / 1152u;
  const int h0 = (int)((tile/6u)*16u);
  const int w0 = (int)((tile%6u)*16u);
  #pragma unroll
  for(int i=0;i<2;i++){
    const float* src = i ? xi : xr;
    #pragma unroll
    for(int dz=0;dz<3;dz++){
      const int tt = (int)t + dz - 1;
      if(tt >= 0 && tt < 32){
        const float* sp = src + (size_t)(b*32u + (unsigned)tt)*9216u;
        float* dp = sm + (i*3+dz)*360;
        for(int e = tid; e < 324; e += 256){
          const int r = e/18, c = e - r*18;
          const int hh = h0-1+r, ww = w0-1+c;
          if(hh>=0 && hh<96 && ww>=0 && ww<96)
            dp[r*20 + c] = sp[hh*96 + ww];
        }
      }
    }
  }
  __syncthreads();

  s16x8 wh[8], wl[8];
  #pragma unroll
  for(int f=0; f<8; f++){
    const int nt = f>>1, ks = f&1;
    const int n  = nt*16 + ln;
    const int k0 = ks*32 + q*8;
    unsigned hp[4], lp[4];
    #pragma unroll
    for(int jp=0; jp<4; jp++){
      const int ka = k0 + jp*2, kb = ka + 1;
      const float v0 = (ka < 54) ? enc_w[n*54 + ka] : 0.f;
      const float v1 = (kb < 54) ? enc_w[n*54 + kb] : 0.f;
      const float a0 = trunc_hi(v0), a1 = trunc_hi(v1);
      hp[jp] = cvt_pk_bf16(a0, a1);
      lp[jp] = cvt_pk_bf16(v0 - a0, v1 - a1);
    }
    u32x4 hv = {hp[0],hp[1],hp[2],hp[3]};
    u32x4 lv = {lp[0],lp[1],lp[2],lp[3]};
    wh[f] = __builtin_bit_cast(s16x8, hv);
    wl[f] = __builtin_bit_cast(s16x8, lv);
  }

  int4 of0a = *(const int4*)(offs + 0*32 + q*8);
  int4 of0b = *(const int4*)(offs + 0*32 + q*8 + 4);
  int4 of1a = *(const int4*)(offs + 1*32 + q*8);
  int4 of1b = *(const int4*)(offs + 1*32 + q*8 + 4);
  int ofv[16] = {of0a.x,of0a.y,of0a.z,of0a.w, of0b.x,of0b.y,of0b.z,of0b.w,
                 of1a.x,of1a.y,of1a.z,of1a.w, of1b.x,of1b.y,of1b.z,of1b.w};
  float4 bq[4];
  #pragma unroll
  for(int nt=0;nt<4;nt++) bq[nt] = *(const float4*)(enc_b + nt*16 + q*4);

  const unsigned rowbase = (b*32u+t)*9216u + (unsigned)(h0*96 + w0);

  #pragma unroll
  for(int rt=0; rt<4; rt++){
    const int R  = wave*4 + rt;
    const int pb = R*20 + ln;
    s16x8 bh[2], bl[2];
    #pragma unroll
    for(int ks=0; ks<2; ks++){
      unsigned hp[4], lp[4];
      #pragma unroll
      for(int jp=0; jp<4; jp++){
        const float v0 = sm[pb + ofv[ks*8 + jp*2 + 0]];
        const float v1 = sm[pb + ofv[ks*8 + jp*2 + 1]];
        const float a0 = trunc_hi(v0), a1 = trunc_hi(v1);
        hp[jp] = cvt_pk_bf16(a0, a1);
        lp[jp] = cvt_pk_bf16(v0 - a0, v1 - a1);
      }
      u32x4 hv = {hp[0],hp[1],hp[2],hp[3]};
      u32x4 lv = {lp[0],lp[1],lp[2],lp[3]};
      bh[ks] = __builtin_bit_cast(s16x8, hv);
      bl[ks] = __builtin_bit_cast(s16x8, lv);
    }
    const size_t pgi = (size_t)(rowbase + (unsigned)(R*96 + ln));
    #pragma unroll
    for(int nt=0; nt<4; nt++){
      f32x4 acc = {0.f,0.f,0.f,0.f};
      #pragma unroll
      for(int ks=0; ks<2; ks++){
        acc = __builtin_amdgcn_mfma_f32_16x16x32_bf16(wh[nt*2+ks], bh[ks], acc, 0,0,0);
        acc = __builtin_amdgcn_mfma_f32_16x16x32_bf16(wh[nt*2+ks], bl[ks], acc, 0,0,0);
        acc = __builtin_amdgcn_mfma_f32_16x16x32_bf16(wl[nt*2+ks], bh[ks], acc, 0,0,0);
      }
      const float v0 = acc[0] + bq[nt].x;
      const float v1 = acc[1] + bq[nt].y;
      const float v2 = acc[2] + bq[nt].z;
      const float v3 = acc[3] + bq[nt].w;
      const float a0 = trunc_hi(v0), a1 = trunc_hi(v1);
      const float a2 = trunc_hi(v2), a3 = trunc_hi(v3);
      const unsigned h01 = cvt_pk_bf16(a0, a1);
      const unsigned h23 = cvt_pk_bf16(a2, a3);
      const unsigned l01 = cvt_pk_bf16(v0 - a0, v1 - a1);
      const unsigned l23 = cvt_pk_bf16(v2 - a2, v3 - a3);
      *(uint2*)(fhi + pgi*64u + (unsigned)(nt*16 + q*4)) = make_uint2(h01, h23);
      *(uint2*)(flo + pgi*64u + (unsigned)(nt*16 + q*4)) = make_uint2(l01, l23);
    }
  }
}

// ---------------- fused SIREN MLP + lerp, MFMA 16x16x32 bf16, RT=4 ----------
// R18: weights staged in 64KB LDS (W1 once; W2 per-cg double-buffered).
// All weight reads = conflict-free ds_read_b128. setprio(1) around MFMA.
__global__ __launch_bounds__(256, 2) void mlp_kernel(
  const float* __restrict__ tcoord,
  const short* __restrict__ fhi, const short* __restrict__ flo,
  const short* __restrict__ W1F, const short* __restrict__ W1FL,
  const float* __restrict__ W1,  const float* __restrict__ b1,
  const short* __restrict__ W2F, const float* __restrict__ b2,
  const float* __restrict__ W3,  const float* __restrict__ b3,
  float* __restrict__ out)
{
  __shared__ __align__(16) short wlds[32768];   // exactly 64KB -> 2 blocks/CU
  const int tid  = threadIdx.x;
  const int wave = tid>>6;
  const int lane = tid&63;
  const int q  = lane>>4;   // quad
  const int ln = lane&15;
  const int l16 = lane*8;
  const unsigned evbase = blockIdx.x*256u + (unsigned)wave*64u;

  // ---- stage W1 hi(chunks 0..31)+lo(32..63) into LDS, 16 chunks/wave ----
  #pragma unroll
  for(int i=0;i<16;i++){
    const int chunk = wave*16 + i;
    const short* g = (chunk < 32) ? (W1F + chunk*512 + l16)
                                  : (W1FL + (chunk-32)*512 + l16);
    *(uint4*)(wlds + chunk*512 + l16) = *(const uint4*)g;
  }

  // ---- per-lane meta for eval (evbase + lane) ----
  const unsigned ev = evbase + (unsigned)lane;
  const unsigned pt = ev>>1;
  const unsigned fc = ev&1u;
  const unsigned wq = pt%96u;
  const unsigned hq = (pt/96u)%96u;
  const unsigned jq = (pt/9216u)%32u;
  const unsigned bq = pt/294912u;
  float tc = tcoord[bq*32u+jq];
  tc = fminf(fmaxf(tc, -1.0f), 1.0f - 1e-6f);
  const float dstep = 2.0f/31.0f;
  const int ti = (int)floorf((tc+1.0f)/dstep);
  const unsigned trow = (unsigned)ti + fc;       // <= 31
  const unsigned rowoff = (bq*32u+trow)*9216u + hq*96u + wq;

  // per row-tile rt: feature row offset + own-eval tc
  float tcv[4];
  s16x8 ahi[4][2], alo[4][2];
  #pragma unroll
  for(int rt=0;rt<4;rt++){
    const unsigned offr = __shfl(rowoff, rt*16 + ln, 64);
    tcv[rt] = __shfl(tc, rt*16 + ln, 64);
    const size_t o = (size_t)offr*64u + (size_t)(q*8);
    ahi[rt][0] = *(const s16x8*)(fhi+o);  ahi[rt][1] = *(const s16x8*)(fhi+o+32);
    alo[rt][0] = *(const s16x8*)(flo+o);  alo[rt][1] = *(const s16x8*)(flo+o+32);
  }

  __syncthreads();   // W1 staged

  // ---- layer 1 (swapped): lane keeps h1 of its own eval row ----
  u32x4 a2w[4][8];
  #pragma unroll
  for(int nt=0; nt<16; nt++){
    const int nb = nt<<4;
    const s16x8 bf0 = *(const s16x8*)(wlds + (nt*2+0)*512 + l16);
    const s16x8 bf1 = *(const s16x8*)(wlds + (nt*2+1)*512 + l16);
    const s16x8 bl0 = *(const s16x8*)(wlds + 16384 + (nt*2+0)*512 + l16);
    const s16x8 bl1 = *(const s16x8*)(wlds + 16384 + (nt*2+1)*512 + l16);
    const float4 b1q = *(const float4*)(b1 + nb + q*4);           // b1[n] (raw)
    const float4 w1q = *(const float4*)(W1 + 64*256 + nb + q*4);  // W1[64][n] (raw)
    #pragma unroll
    for(int rt=0;rt<4;rt++){
      f32x4 acc = {0.f,0.f,0.f,0.f};
      __builtin_amdgcn_s_setprio(1);
      acc = __builtin_amdgcn_mfma_f32_16x16x32_bf16(bf0, ahi[rt][0], acc, 0,0,0);
      acc = __builtin_amdgcn_mfma_f32_16x16x32_bf16(bf1, ahi[rt][1], acc, 0,0,0);
      acc = __builtin_amdgcn_mfma_f32_16x16x32_bf16(bf0, alo[rt][0], acc, 0,0,0);
      acc = __builtin_amdgcn_mfma_f32_16x16x32_bf16(bf1, alo[rt][1], acc, 0,0,0);
      acc = __builtin_amdgcn_mfma_f32_16x16x32_bf16(bl0, ahi[rt][0], acc, 0,0,0);
      acc = __builtin_amdgcn_mfma_f32_16x16x32_bf16(bl1, ahi[rt][1], acc, 0,0,0);
      __builtin_amdgcn_s_setprio(0);
      const float tcr = tcv[rt];
      const float s0 = sin_rev(fmaf(SREV, fmaf(tcr, w1q.x, b1q.x), acc[0]));
      const float s1 = sin_rev(fmaf(SREV, fmaf(tcr, w1q.y, b1q.y), acc[1]));
      const float s2 = sin_rev(fmaf(SREV, fmaf(tcr, w1q.z, b1q.z), acc[2]));
      const float s3 = sin_rev(fmaf(SREV, fmaf(tcr, w1q.w, b1q.w), acc[3]));
      a2w[rt][nt>>1][(nt&1)*2+0] = cvt_pk_bf16(s0,s1);
      a2w[rt][nt>>1][(nt&1)*2+1] = cvt_pk_bf16(s2,s3);
    }
  }

  __syncthreads();   // everyone done reading W1 from LDS

  // ---- stage W2 cg0 into half A ----
  #pragma unroll
  for(int c=0;c<8;c++){
    const int chunk = wave*8 + c;             // 0..31
    *(uint4*)(wlds + chunk*512 + l16) = *(const uint4*)(W2F + chunk*512 + l16);
  }
  __syncthreads();   // cg0 staged

  // ---- layer 2 (+3 folded), per-cg LDS double-buffer ----
  float pacc[4][4];
  #pragma unroll
  for(int rt=0;rt<4;rt++)
    #pragma unroll
    for(int rr=0;rr<4;rr++) pacc[rt][rr]=0.f;

  #pragma unroll 1
  for(int cg=0; cg<4; cg++){
    const int half = (cg&1)*16384;
    // prefetch next cg into the other half (its prior readers are done)
    if(cg < 3){
      const int nhalf = ((cg+1)&1)*16384;
      #pragma unroll
      for(int c=0;c<8;c++){
        const int chunk = wave*8 + c;
        *(uint4*)(wlds + nhalf + chunk*512 + l16)
          = *(const uint4*)(W2F + ((cg+1)*32 + chunk)*512 + l16);
      }
    }
    #pragma unroll
    for(int nt=0;nt<4;nt++){
      f32x4 acc2[4];
      const f32x4 zv = {0.f,0.f,0.f,0.f};
      #pragma unroll
      for(int rt=0;rt<4;rt++) acc2[rt] = zv;
      __builtin_amdgcn_s_setprio(1);
      #pragma unroll
      for(int ks=0; ks<8; ks++){
        const s16x8 bfr = *(const s16x8*)(wlds + half + (nt*8+ks)*512 + l16);
        #pragma unroll
        for(int rt=0;rt<4;rt++){
          const s16x8 a2 = __builtin_bit_cast(s16x8, a2w[rt][ks]);
          acc2[rt] = __builtin_amdgcn_mfma_f32_16x16x32_bf16(a2, bfr, acc2[rt], 0,0,0);
        }
      }
      __builtin_amdgcn_s_setprio(0);
      const int n = cg*64 + nt*16 + ln;
      const float sb2 = SREV * b2[n];
      const float w3v = W3[n];
      #pragma unroll
      for(int rt=0;rt<4;rt++)
        #pragma unroll
        for(int rr=0;rr<4;rr++){
          const float h2 = sin_rev(acc2[rt][rr] + sb2);
          pacc[rt][rr] += h2*w3v;
        }
    }
    __syncthreads();   // cg consumed; next cg's staging visible after this
  }

  // reduce over the 16 n-lanes (xor within ln bits keeps q fixed)
  #pragma unroll
  for(int rt=0;rt<4;rt++)
    #pragma unroll
    for(int rr=0;rr<4;rr++){
      float v = pacc[rt][rr];
      v += __shfl_xor(v, 1, 64);
      v += __shfl_xor(v, 2, 64);
      v += __shfl_xor(v, 4, 64);
      v += __shfl_xor(v, 8, 64);
      pacc[rt][rr] = v;
    }

  // ---- fused lerp: rows (2s, 2s+1) = (floor, ceil) of one pixel ----
  float tcp_[4][2];
  #pragma unroll
  for(int rt=0;rt<4;rt++)
    #pragma unroll
    for(int s=0;s<2;s++)
      tcp_[rt][s] = __shfl(tc, rt*16 + q*4 + 2*s, 64);

  if(ln==0){
    const float b3v = b3[0];
    #pragma unroll
    for(int rt=0;rt<4;rt++){
      #pragma unroll
      for(int s=0;s<2;s++){
        const int m0 = rt*16 + q*4 + 2*s;
        const float tcp = tcp_[rt][s];
        const int tip = (int)floorf((tcp+1.0f)/dstep);
        const float fci = (float)((double)tip*(2.0/31.0) - 1.0);
        const float tau = (tcp - fci)/dstep;
        const unsigned px = (evbase + (unsigned)m0)>>1;
        out[px] = pacc[rt][2*s]*(1.0f-tau) + pacc[rt][2*s+1]*tau + b3v;
      }
    }
  }
}

extern "C" void kernel_launch(void* const* d_in, const int* in_sizes, int n_in,
                              void* d_out, int out_size, void* d_ws, size_t ws_size,
                              hipStream_t stream){
  const float* xr     = (const float*)d_in[0];
  const float* xi     = (const float*)d_in[1];
  const float* tcoord = (const float*)d_in[2];
  const float* enc_w  = (const float*)d_in[3];
  const float* enc_b  = (const float*)d_in[4];
  const float* W1     = (const float*)d_in[5];
  const float* b1     = (const float*)d_in[6];
  const float* W2     = (const float*)d_in[7];
  const float* b2     = (const float*)d_in[8];
  const float* W3     = (const float*)d_in[9];
  const float* b3     = (const float*)d_in[10];

  char* ws = (char*)d_ws;
  short* fhi  = (short*)(ws);
  short* flo  = (short*)(ws + 75497472);
  short* W1F  = (short*)(ws + 150994944);
  short* W1FL = (short*)(ws + 151027712);
  short* W2F  = (short*)(ws + 151060480);
  float* out  = (float*)d_out;

  hipLaunchKernelGGL(prep_kernel, dim3(64),   dim3(256), 0, stream, W1, W2, W1F, W1FL, W2F);
  hipLaunchKernelGGL(conv_kernel, dim3(2304), dim3(256), 0, stream, xr, xi, enc_w, enc_b, fhi, flo);
  hipLaunchKernelGGL(mlp_kernel,  dim3(4608), dim3(256), 0, stream, tcoord, fhi, flo,
                     W1F, W1FL, W1, b1, W2F, b2, W3, b3, out);
}